// Round 3
// baseline (745.505 us; speedup 1.0000x reference)
//
#include <hip/hip_runtime.h>
#include <hip/hip_bf16.h>

// Problem constants
#define TB 2
#define TS 2048
#define TD 1024
#define TH 16
#define THD 64
#define TE 8
#define TKK 2
#define TF 4096
#define TT (TB*TS)      // 4096 tokens
#define QLD (3*TD)      // 3072

typedef unsigned short u16;
typedef __attribute__((ext_vector_type(8))) __bf16 bf16x8;
typedef __attribute__((ext_vector_type(8))) u16 u16x8;
typedef __attribute__((ext_vector_type(4))) u16 u16x4;
typedef __attribute__((ext_vector_type(4))) float f32x4;

static __device__ __forceinline__ u16 f2bf(float f){
  __hip_bfloat16 h = __float2bfloat16(f);
  return __builtin_bit_cast(u16, h);
}

#define MFMA16(a,b,c) __builtin_amdgcn_mfma_f32_16x16x32_bf16((a),(b),(c),0,0,0)
#define GLL16(g, l) __builtin_amdgcn_global_load_lds( \
    (const __attribute__((address_space(1))) unsigned int*)(g), \
    (__attribute__((address_space(3))) unsigned int*)(l), 16, 0, 0)

// ---------------------------------------------------------------- utilities
__global__ __launch_bounds__(256)
void cast_bf_kernel(const float* __restrict__ in, u16* __restrict__ out, int n4){
  int i = blockIdx.x*256 + threadIdx.x;
  if (i < n4){
    float4 v = ((const float4*)in)[i];
    u16x4 o = { f2bf(v.x), f2bf(v.y), f2bf(v.z), f2bf(v.w) };
    ((u16x4*)out)[i] = o;
  }
}

// out[z][c][r] = (bf16) in[z][r][c]   (R,C multiples of 32)
__global__ __launch_bounds__(256)
void transpose_cast_kernel(const float* __restrict__ in, u16* __restrict__ out, int R, int C){
  __shared__ float tile[32][33];
  const size_t mo = (size_t)blockIdx.z * R * C;
  const float* ip = in + mo;
  u16* op = out + mo;
  const int c0 = blockIdx.x*32, r0 = blockIdx.y*32;
  const int lx = threadIdx.x & 31, ly = threadIdx.x >> 5;   // 32 x 8
#pragma unroll
  for (int i2 = 0; i2 < 4; ++i2)
    tile[ly + i2*8][lx] = ip[(size_t)(r0 + ly + i2*8)*C + c0 + lx];
  __syncthreads();
#pragma unroll
  for (int i2 = 0; i2 < 4; ++i2)
    op[(size_t)(c0 + ly + i2*8)*R + r0 + lx] = f2bf(tile[lx][ly + i2*8]);
}

__global__ void zero_counts_kernel(int* counts){
  if (threadIdx.x < TE) counts[threadIdx.x] = 0;
}

// ---------------------------------------------------------------- layernorm 1
__global__ __launch_bounds__(256)
void ln1_kernel(const float* __restrict__ x, const float* __restrict__ g,
                const float* __restrict__ bb, u16* __restrict__ h){
  const int t = blockIdx.x, tid = threadIdx.x;
  const float4 v = ((const float4*)(x + (size_t)t*TD))[tid];
  float s  = v.x + v.y + v.z + v.w;
  float ss = v.x*v.x + v.y*v.y + v.z*v.z + v.w*v.w;
#pragma unroll
  for (int d = 32; d >= 1; d >>= 1){ s += __shfl_down(s, d); ss += __shfl_down(ss, d); }
  __shared__ float red[8];
  const int lane = tid & 63, wave = tid >> 6;
  if (lane == 0){ red[wave] = s; red[4+wave] = ss; }
  __syncthreads();
  const float S  = red[0]+red[1]+red[2]+red[3];
  const float SS = red[4]+red[5]+red[6]+red[7];
  const float mu = S * (1.f/TD);
  const float rstd = rsqrtf(SS*(1.f/TD) - mu*mu + 1e-5f);
  const float4 gv = ((const float4*)g)[tid];
  const float4 bv = ((const float4*)bb)[tid];
  u16x4 o = { f2bf((v.x-mu)*rstd*gv.x + bv.x),
              f2bf((v.y-mu)*rstd*gv.y + bv.y),
              f2bf((v.z-mu)*rstd*gv.z + bv.z),
              f2bf((v.w-mu)*rstd*gv.w + bv.w) };
  ((u16x4*)(h + (size_t)t*TD))[tid] = o;
}

// ------------------------------------------------- layernorm 2 + fp32 router
__global__ __launch_bounds__(256)
void ln2_router_kernel(const float* __restrict__ xo, const float* __restrict__ g,
                       const float* __restrict__ bb, u16* __restrict__ h2,
                       const float* __restrict__ rw, const float* __restrict__ rb,
                       int* __restrict__ counts, int* __restrict__ topidx,
                       float* __restrict__ topw){
  const int t = blockIdx.x, tid = threadIdx.x;
  const float4 v = ((const float4*)(xo + (size_t)t*TD))[tid];
  float s  = v.x + v.y + v.z + v.w;
  float ss = v.x*v.x + v.y*v.y + v.z*v.z + v.w*v.w;
#pragma unroll
  for (int d = 32; d >= 1; d >>= 1){ s += __shfl_down(s, d); ss += __shfl_down(ss, d); }
  __shared__ float red[8];
  const int lane = tid & 63, wave = tid >> 6;
  if (lane == 0){ red[wave] = s; red[4+wave] = ss; }
  __syncthreads();
  const float S  = red[0]+red[1]+red[2]+red[3];
  const float SS = red[4]+red[5]+red[6]+red[7];
  const float mu = S * (1.f/TD);
  const float rstd = rsqrtf(SS*(1.f/TD) - mu*mu + 1e-5f);
  const float4 gv = ((const float4*)g)[tid];
  const float4 bv = ((const float4*)bb)[tid];
  float hv[4] = { (v.x-mu)*rstd*gv.x + bv.x, (v.y-mu)*rstd*gv.y + bv.y,
                  (v.z-mu)*rstd*gv.z + bv.z, (v.w-mu)*rstd*gv.w + bv.w };
  u16x4 o = { f2bf(hv[0]), f2bf(hv[1]), f2bf(hv[2]), f2bf(hv[3]) };
  ((u16x4*)(h2 + (size_t)t*TD))[tid] = o;

  float acc[TE] = {0,0,0,0,0,0,0,0};
#pragma unroll
  for (int q = 0; q < 4; ++q){
    const int d = tid*4 + q;
    const float4 r0 = ((const float4*)(rw + (size_t)d*TE))[0];
    const float4 r1 = ((const float4*)(rw + (size_t)d*TE))[1];
    acc[0] += hv[q]*r0.x; acc[1] += hv[q]*r0.y; acc[2] += hv[q]*r0.z; acc[3] += hv[q]*r0.w;
    acc[4] += hv[q]*r1.x; acc[5] += hv[q]*r1.y; acc[6] += hv[q]*r1.z; acc[7] += hv[q]*r1.w;
  }
#pragma unroll
  for (int d = 32; d >= 1; d >>= 1)
#pragma unroll
    for (int e = 0; e < TE; ++e) acc[e] += __shfl_down(acc[e], d);
  __shared__ float racc[4][TE];
  if (lane == 0)
#pragma unroll
    for (int e = 0; e < TE; ++e) racc[wave][e] = acc[e];
  __syncthreads();
  if (tid == 0){
    float lg[TE];
#pragma unroll
    for (int e = 0; e < TE; ++e)
      lg[e] = racc[0][e] + racc[1][e] + racc[2][e] + racc[3][e] + rb[e];
    int e1 = 0;
    for (int e = 1; e < TE; ++e) if (lg[e] > lg[e1]) e1 = e;
    int e2 = -1;
    for (int e = 0; e < TE; ++e){ if (e == e1) continue; if (e2 < 0 || lg[e] > lg[e2]) e2 = e; }
    const float w1 = 1.f / (1.f + __expf(lg[e2] - lg[e1]));
    const float w2 = 1.f / (1.f + __expf(lg[e1] - lg[e2]));
    topidx[t*2]   = e1;  topidx[t*2+1] = e2;
    topw[t*2]     = w1;  topw[t*2+1]   = w2;
    atomicAdd(&counts[e1], 1);
    atomicAdd(&counts[e2], 1);
  }
}

__global__ void offsets_kernel(const int* __restrict__ counts, int* __restrict__ offs,
                               int* __restrict__ cursors, float* __restrict__ load_out){
  if (threadIdx.x == 0){
    int off = 0;
    for (int e = 0; e < TE; ++e){
      offs[e] = off; cursors[e] = off; off += counts[e];
      load_out[e] = (float)counts[e];
    }
  }
}

__global__ __launch_bounds__(256)
void scatter_kernel(const int* __restrict__ topidx, const float* __restrict__ topw,
                    int* __restrict__ cursors, int* __restrict__ assign_tok,
                    float* __restrict__ assign_w, int* __restrict__ token_slot){
  const int t = blockIdx.x*256 + threadIdx.x;
  if (t >= TT) return;
#pragma unroll
  for (int k = 0; k < 2; ++k){
    const int e = topidx[t*2 + k];
    const int pos = atomicAdd(&cursors[e], 1);
    assign_tok[pos] = t;
    assign_w[pos]   = topw[t*2 + k];
    token_slot[t*2 + k] = pos;
  }
}

// ------------------------------------------ 256x256 8-phase GEMM (T2+T3+T4+T5)
// C[256,256] tile; 8 waves (2M x 4N), per-wave 128x64; BK=64, 2 K-tiles/iter,
// 8 phases/iter; LDS 128KB: [buf][op][half] of 128x64 bf16, st_16x32 swizzled
// (linear global_load_lds dest + inverse-swizzled global source + swizzled
// ds_read). vmcnt(4) at phases 4/8; quadrant order (0,0)(1,0)(0,1)(1,1).
// MODE 0: QKV  out_bf = acc + bias                   (A dense rows)
// MODE 2: MOE1 out_bf = gelu(acc + b1[e])            (A rows gathered)
// MODE 3: MOE2 out_f  = (acc + b2[e]) * assign_w     (A rows = slots)
#define LD8(base, off) (*(const bf16x8*)((const char*)(base) + (off)))
#define STG2(rp, ktv, dst) do{ \
    GLL16((rp)[0] + (size_t)(ktv)*64, (dst) + tid*8); \
    GLL16((rp)[1] + (size_t)(ktv)*64, (dst) + 4096 + tid*8); }while(0)

#define PHASE(AB, BB, QR, QC, STAGES, WAITS) do{ \
    bf16x8 xa0=LD8(AB,offA[0][0]), xa1=LD8(AB,offA[1][0]), xa2=LD8(AB,offA[2][0]), xa3=LD8(AB,offA[3][0]); \
    bf16x8 ya0=LD8(AB,offA[0][1]), ya1=LD8(AB,offA[1][1]), ya2=LD8(AB,offA[2][1]), ya3=LD8(AB,offA[3][1]); \
    bf16x8 xb0=LD8(BB,offB[0][0]), xb1=LD8(BB,offB[1][0]); \
    bf16x8 yb0=LD8(BB,offB[0][1]), yb1=LD8(BB,offB[1][1]); \
    STAGES; \
    __builtin_amdgcn_s_barrier(); \
    asm volatile("s_waitcnt lgkmcnt(0)" ::: "memory"); \
    __builtin_amdgcn_sched_barrier(0); \
    __builtin_amdgcn_s_setprio(1); \
    acc[QR][QC][0][0]=MFMA16(xa0,xb0,acc[QR][QC][0][0]); acc[QR][QC][0][0]=MFMA16(ya0,yb0,acc[QR][QC][0][0]); \
    acc[QR][QC][1][0]=MFMA16(xa1,xb0,acc[QR][QC][1][0]); acc[QR][QC][1][0]=MFMA16(ya1,yb0,acc[QR][QC][1][0]); \
    acc[QR][QC][2][0]=MFMA16(xa2,xb0,acc[QR][QC][2][0]); acc[QR][QC][2][0]=MFMA16(ya2,yb0,acc[QR][QC][2][0]); \
    acc[QR][QC][3][0]=MFMA16(xa3,xb0,acc[QR][QC][3][0]); acc[QR][QC][3][0]=MFMA16(ya3,yb0,acc[QR][QC][3][0]); \
    acc[QR][QC][0][1]=MFMA16(xa0,xb1,acc[QR][QC][0][1]); acc[QR][QC][0][1]=MFMA16(ya0,yb1,acc[QR][QC][0][1]); \
    acc[QR][QC][1][1]=MFMA16(xa1,xb1,acc[QR][QC][1][1]); acc[QR][QC][1][1]=MFMA16(ya1,yb1,acc[QR][QC][1][1]); \
    acc[QR][QC][2][1]=MFMA16(xa2,xb1,acc[QR][QC][2][1]); acc[QR][QC][2][1]=MFMA16(ya2,yb1,acc[QR][QC][2][1]); \
    acc[QR][QC][3][1]=MFMA16(xa3,xb1,acc[QR][QC][3][1]); acc[QR][QC][3][1]=MFMA16(ya3,yb1,acc[QR][QC][3][1]); \
    __builtin_amdgcn_s_setprio(0); \
    WAITS; \
    __builtin_amdgcn_s_barrier(); \
  }while(0)

template<int MODE>
__global__ __launch_bounds__(512, 2)
void gemm256(const u16* __restrict__ A, const u16* __restrict__ Bt,
             const float* __restrict__ bias,
             float* __restrict__ outF, u16* __restrict__ outB,
             const int K, const int N,
             const int* __restrict__ counts, const int* __restrict__ offs,
             const int* __restrict__ assign_tok, const float* __restrict__ assign_w)
{
  __shared__ u16 lds[8][8192];   // [buf*4 + op*2 + half][128*64]
  const int tid = threadIdx.x;
  const int n0 = blockIdx.x*256;
  int row0 = 0, slotbase = 0, cntRem = 256, slotEnd = 0;
  if (MODE == 0){
    row0 = blockIdx.y*256;
  } else {
    const int e = blockIdx.y >> 4, mt = blockIdx.y & 15;
    const int cnt = counts[e];
    if (mt*256 >= cnt) return;
    slotbase = offs[e] + mt*256;
    slotEnd  = offs[e] + cnt;
    cntRem   = cnt - mt*256; if (cntRem > 256) cntRem = 256;
    Bt   += (size_t)e*K*N;
    bias += (size_t)e*N;
  }
  // staging: thread t covers LDS rows (t>>3) and 64+(t>>3) of each half;
  // inverse-swizzled global column so linear LDS dest + swizzled read match.
  const int srow = tid >> 3;
  const int csrc = ((tid & 7)*8) ^ (((tid >> 5) & 1) << 4);
  const u16* aRow[4]; const u16* bRow[4];
#pragma unroll
  for (int p = 0; p < 4; ++p){
    const int r = p*64 + srow;
    if (MODE == 0){
      aRow[p] = A + (size_t)(row0 + r)*K + csrc;
    } else if (MODE == 2){
      int s2 = slotbase + r; if (s2 > slotEnd-1) s2 = slotEnd-1;
      aRow[p] = A + (size_t)assign_tok[s2]*K + csrc;
    } else {
      int s2 = slotbase + r; if (s2 > slotEnd-1) s2 = slotEnd-1;
      aRow[p] = A + (size_t)s2*K + csrc;
    }
    bRow[p] = Bt + (size_t)(n0 + r)*K + csrc;
  }
  u16* LA0[2] = { lds[0], lds[1] };
  u16* LB0[2] = { lds[2], lds[3] };
  u16* LA1[2] = { lds[4], lds[5] };
  u16* LB1[2] = { lds[6], lds[7] };

  const int lane = tid & 63, wave = tid >> 6;
  const int wr = wave >> 2, wc = wave & 3;
  const int r16 = lane & 15, kgr = lane >> 4;
  int offA[4][2], offB[2][2];
#pragma unroll
  for (int f = 0; f < 4; ++f)
#pragma unroll
    for (int kk = 0; kk < 2; ++kk){
      int by = (wr*64 + f*16 + r16)*128 + kk*64 + kgr*16;
      offA[f][kk] = by ^ (((by>>9)&1)<<5);
    }
#pragma unroll
  for (int g = 0; g < 2; ++g)
#pragma unroll
    for (int kk = 0; kk < 2; ++kk){
      int by = (wc*32 + g*16 + r16)*128 + kk*64 + kgr*16;
      offB[g][kk] = by ^ (((by>>9)&1)<<5);
    }
  const f32x4 z4 = {0.f,0.f,0.f,0.f};
  f32x4 acc[2][2][4][2];
#pragma unroll
  for (int a0 = 0; a0 < 2; ++a0)
#pragma unroll
    for (int a1 = 0; a1 < 2; ++a1)
#pragma unroll
      for (int a2 = 0; a2 < 4; ++a2)
#pragma unroll
        for (int a3 = 0; a3 < 2; ++a3) acc[a0][a1][a2][a3] = z4;

  // prologue: T0 fully + T1.B0 + T1.A0 ; keep last 2 halves in flight
  STG2(aRow+0, 0, LA0[0]); STG2(aRow+2, 0, LA0[1]);
  STG2(bRow+0, 0, LB0[0]); STG2(bRow+2, 0, LB0[1]);
  STG2(bRow+0, 1, LB1[0]); STG2(aRow+0, 1, LA1[0]);
  asm volatile("s_waitcnt vmcnt(4)" ::: "memory");
  __builtin_amdgcn_s_barrier();

  const int NT = K >> 6, niter = NT >> 1;
  for (int it2 = 0; it2 < niter; ++it2){
    const int kt = it2*2;
    const bool last = (it2 == niter-1);
    PHASE(LA0[0], LB0[0], 0,0, { STG2(aRow+2, kt+1, LA1[1]); }, {});
    PHASE(LA0[1], LB0[0], 1,0, { STG2(bRow+2, kt+1, LB1[1]); }, {});
    PHASE(LA0[0], LB0[1], 0,1, { if(!last) STG2(bRow+0, kt+2, LB0[0]); }, {});
    PHASE(LA0[1], LB0[1], 1,1, { if(!last) STG2(aRow+0, kt+2, LA0[0]); },
          { if(last) asm volatile("s_waitcnt vmcnt(0)":::"memory");
            else     asm volatile("s_waitcnt vmcnt(4)":::"memory"); });
    PHASE(LA1[0], LB1[0], 0,0, { if(!last) STG2(aRow+2, kt+2, LA0[1]); }, {});
    PHASE(LA1[1], LB1[0], 1,0, { if(!last) STG2(bRow+2, kt+2, LB0[1]); }, {});
    PHASE(LA1[0], LB1[1], 0,1, { if(!last) STG2(bRow+0, kt+3, LB1[0]); }, {});
    PHASE(LA1[1], LB1[1], 1,1, { if(!last) STG2(aRow+0, kt+3, LA1[0]); },
          { if(!last) asm volatile("s_waitcnt vmcnt(4)":::"memory"); });
  }

  // epilogue
#pragma unroll
  for (int qr = 0; qr < 2; ++qr)
#pragma unroll
  for (int f = 0; f < 4; ++f)
#pragma unroll
  for (int rr = 0; rr < 4; ++rr){
    const int rl = qr*128 + wr*64 + f*16 + kgr*4 + rr;
#pragma unroll
    for (int qc = 0; qc < 2; ++qc)
#pragma unroll
    for (int g = 0; g < 2; ++g){
      const int col = n0 + qc*128 + wc*32 + g*16 + r16;
      float v = acc[qr][qc][f][g][rr];
      if (MODE == 0){
        outB[(size_t)(row0 + rl)*QLD + col] = f2bf(v + bias[col]);
      } else if (MODE == 2){
        if (rl < cntRem){
          v += bias[col];
          const float t = tanhf(0.7978845608028654f*(v + 0.044715f*v*v*v));
          outB[(size_t)(slotbase + rl)*TF + col] = f2bf(0.5f*v*(1.f + t));
        }
      } else {
        if (rl < cntRem)
          outF[(size_t)(slotbase + rl)*TD + col] = (v + bias[col])*assign_w[slotbase + rl];
      }
    }
  }
}

// ---------------------------------------------------------------- GEMM 128^2
// (kept for O-proj: N=1024 would under-fill the chip at 256^2 tiles)
template<int MODE>
__global__ __launch_bounds__(256)
void gemm_bt(const u16* __restrict__ A, const u16* __restrict__ Bt,
             const float* __restrict__ bias, const float* __restrict__ resid,
             float* __restrict__ outF, u16* __restrict__ outB,
             int K, int N,
             const int* __restrict__ counts, const int* __restrict__ offs,
             const int* __restrict__ assign_tok, const float* __restrict__ assign_w)
{
  __shared__ u16 As[2][128*32];
  __shared__ u16 Bs[2][128*32];
  const int tid = threadIdx.x;
  const int n0  = blockIdx.x * 128;
  int row0 = blockIdx.y * 128;
  const int srow = tid >> 2, skseg = tid & 3;
  const u16* aptr[2];
  const u16* bptr[2];
#pragma unroll
  for (int it = 0; it < 2; ++it){
    const int r = it*64 + srow;
    aptr[it] = A + (size_t)(row0 + r)*K + skseg*8;
    bptr[it] = Bt + (size_t)(n0 + it*64 + srow)*K + skseg*8;
  }

#define STAGE(buf, kt) do {                                        \
    _Pragma("unroll")                                              \
    for (int it = 0; it < 2; ++it){                                \
      GLL16(aptr[it] + (size_t)(kt)*32, &As[buf][it*2048 + tid*8]);\
      GLL16(bptr[it] + (size_t)(kt)*32, &Bs[buf][it*2048 + tid*8]);\
    } } while(0)

  const int lane = tid & 63, wave = tid >> 6;
  const int wm = (wave >> 1) * 64, wn = (wave & 1) * 64;
  const int r16 = lane & 15, kgr = lane >> 4;
  const f32x4 z4 = {0.f,0.f,0.f,0.f};
  f32x4 acc[4][4];
#pragma unroll
  for (int i = 0; i < 4; ++i)
#pragma unroll
    for (int j = 0; j < 4; ++j) acc[i][j] = z4;

  STAGE(0, 0);
  __syncthreads();
  const int nk = K >> 5;
  for (int kt = 0; kt < nk; ++kt){
    const int cur = kt & 1;
    if (kt + 1 < nk) STAGE(cur ^ 1, kt + 1);
    bf16x8 a[4], b[4];
#pragma unroll
    for (int i = 0; i < 4; ++i)
      a[i] = *(const bf16x8*)&As[cur][(wm + i*16 + r16)*32 + kgr*8];
#pragma unroll
    for (int j = 0; j < 4; ++j)
      b[j] = *(const bf16x8*)&Bs[cur][(wn + j*16 + r16)*32 + kgr*8];
#pragma unroll
    for (int i = 0; i < 4; ++i)
#pragma unroll
      for (int j = 0; j < 4; ++j)
        acc[i][j] = MFMA16(a[i], b[j], acc[i][j]);
    __syncthreads();
  }
#undef STAGE

#pragma unroll
  for (int i = 0; i < 4; ++i){
#pragma unroll
    for (int r = 0; r < 4; ++r){
      const int row = wm + i*16 + kgr*4 + r;
#pragma unroll
      for (int j = 0; j < 4; ++j){
        const int col = n0 + wn + j*16 + r16;
        float v = acc[i][j][r];
        const size_t idx = (size_t)(row0 + row)*TD + col;
        outF[idx] = v + bias[col] + resid[idx];
      }
    }
  }
  (void)counts; (void)offs; (void)assign_tok; (void)assign_w; (void)outB; (void)N;
}

// ------------------------------------------------------- flash attention
__global__ __launch_bounds__(256)
void attn_kernel(const u16* __restrict__ qkv, u16* __restrict__ ctx){
  const int blk = blockIdx.x;
  const int pq = blk & 15, bh = blk >> 4;
  const int b = bh >> 4, h = bh & 15;
  const int tid = threadIdx.x, lane = tid & 63, wave = tid >> 6;
  const int r16 = lane & 15, kgr = lane >> 4;
  const size_t base = (size_t)b * TS * QLD;
  const u16* Q  = qkv + base + h*THD;
  const u16* Kp = qkv + base + TD + h*THD;
  const u16* Vp = qkv + base + 2*TD + h*THD;

  __shared__ u16 VT[2][64*64];     // V^T [hd][kv], XOR-swizzled
  __shared__ u16 Plds[4][16*64];   // per-wave P [q][kv], XOR-swizzled

  const int kvr0 = tid >> 3,          hs0 = tid & 7;
  const int kvr1 = (tid + 256) >> 3,  hs1 = tid & 7;
  const f32x4 z4 = {0.f,0.f,0.f,0.f};

  for (int qsel = 0; qsel < 2; ++qsel){
    const int qt = qsel ? (31 - pq) : pq;
    const int qw = qt*64 + wave*16;

    const bf16x8 qa0 = *(const bf16x8*)&Q[(size_t)(qw + r16)*QLD + kgr*8];
    const bf16x8 qa1 = *(const bf16x8*)&Q[(size_t)(qw + r16)*QLD + 32 + kgr*8];

    f32x4 O[4] = { z4, z4, z4, z4 };
    float m_r = -1e30f;
    float l_r = 0.f;

    u16x8 v0 = *(const u16x8*)&Vp[(size_t)kvr0*QLD + hs0*8];
    u16x8 v1 = *(const u16x8*)&Vp[(size_t)kvr1*QLD + hs1*8];

    __syncthreads();

    for (int kt = 0; kt <= qt; ++kt){
      const int kv0 = kt*64;
      u16* vt = &VT[kt & 1][0];
#pragma unroll
      for (int jj = 0; jj < 8; ++jj)
        vt[((hs0*8 + jj)*64 + kvr0) ^ (hs0<<3)] = v0[jj];
#pragma unroll
      for (int jj = 0; jj < 8; ++jj)
        vt[((hs1*8 + jj)*64 + kvr1) ^ (hs1<<3)] = v1[jj];
      if (kt < qt){
        v0 = *(const u16x8*)&Vp[(size_t)(kv0 + 64 + kvr0)*QLD + hs0*8];
        v1 = *(const u16x8*)&Vp[(size_t)(kv0 + 64 + kvr1)*QLD + hs1*8];
      }
      f32x4 s[4];
      __builtin_amdgcn_s_setprio(1);
#pragma unroll
      for (int j = 0; j < 4; ++j){
        const bf16x8 k0 = *(const bf16x8*)&Kp[(size_t)(kv0 + j*16 + r16)*QLD + kgr*8];
        const bf16x8 k1 = *(const bf16x8*)&Kp[(size_t)(kv0 + j*16 + r16)*QLD + 32 + kgr*8];
        s[j] = MFMA16(k0, qa0, z4);
        s[j] = MFMA16(k1, qa1, s[j]);
      }
      __builtin_amdgcn_s_setprio(0);
      const bool diag = (kt == qt);
      float mx = -3e38f;
#pragma unroll
      for (int j = 0; j < 4; ++j)
#pragma unroll
        for (int r = 0; r < 4; ++r){
          float v = s[j][r] * 0.125f;
          if (diag && (kv0 + j*16 + kgr*4 + r > qw + r16)) v += -1e9f;
          s[j][r] = v;
          mx = fmaxf(mx, v);
        }
      mx = fmaxf(mx, __shfl_xor(mx, 16));
      mx = fmaxf(mx, __shfl_xor(mx, 32));
      const float mn = fmaxf(m_r, mx);
      const float al = __expf(m_r - mn);
      m_r = mn;
      float rs = 0.f;
#pragma unroll
      for (int j = 0; j < 4; ++j){
        u16x4 pw;
#pragma unroll
        for (int r = 0; r < 4; ++r){
          const float p = __expf(s[j][r] - mn);
          rs += p;
          pw[r] = f2bf(p);
        }
        *(u16x4*)&Plds[wave][(r16*64 + j*16 + kgr*4) ^ ((r16&7)<<3)] = pw;
      }
      rs += __shfl_xor(rs, 16);
      rs += __shfl_xor(rs, 32);
      l_r = l_r*al + rs;
      float alr[4];
#pragma unroll
      for (int r = 0; r < 4; ++r)
        alr[r] = __shfl(al, (lane & 48) | (kgr*4 + r));
#pragma unroll
      for (int c = 0; c < 4; ++c)
#pragma unroll
        for (int r = 0; r < 4; ++r) O[c][r] *= alr[r];
      __syncthreads();
      __builtin_amdgcn_s_setprio(1);
#pragma unroll
      for (int kbl = 0; kbl < 2; ++kbl){
        const bf16x8 pa = *(const bf16x8*)&Plds[wave][(r16*64 + kbl*32 + kgr*8) ^ ((r16&7)<<3)];
#pragma unroll
        for (int c = 0; c < 4; ++c){
          const int hd = c*16 + r16;
          const bf16x8 vb = *(const bf16x8*)&vt[(hd*64 + kbl*32 + kgr*8) ^ (((hd>>3)&7)<<3)];
          O[c] = MFMA16(pa, vb, O[c]);
        }
      }
      __builtin_amdgcn_s_setprio(0);
    }
    u16* cp = ctx + (size_t)b*TS*TD + h*THD;
#pragma unroll
    for (int r = 0; r < 4; ++r){
      const float lr = __shfl(l_r, (lane & 48) | (kgr*4 + r));
      const float inv = 1.f / lr;
      const int qrow = qw + kgr*4 + r;
#pragma unroll
      for (int c = 0; c < 4; ++c)
        cp[(size_t)qrow*TD + c*16 + r16] = f2bf(O[c][r] * inv);
    }
  }
}

// ---------------------------------------------------------------- combine
__global__ __launch_bounds__(256)
void combine_kernel(float* __restrict__ out, const float* __restrict__ slot_out,
                    const int* __restrict__ token_slot){
  const int i = blockIdx.x*256 + threadIdx.x;   // over TT*TD/4
  const int t = i >> 8, c = i & 255;
  const int s0 = token_slot[t*2], s1 = token_slot[t*2+1];
  const float4 a = ((const float4*)out)[i];
  const float4 u = ((const float4*)slot_out)[(size_t)s0*256 + c];
  const float4 w = ((const float4*)slot_out)[(size_t)s1*256 + c];
  float4 o = { a.x+u.x+w.x, a.y+u.y+w.y, a.z+u.z+w.z, a.w+u.w+w.w };
  ((float4*)out)[i] = o;
}

// ---------------------------------------------------------------- launcher
extern "C" void kernel_launch(void* const* d_in, const int* in_sizes, int n_in,
                              void* d_out, int out_size, void* d_ws, size_t ws_size,
                              hipStream_t stream){
  const float* x     = (const float*)d_in[0];
  const float* ln1_g = (const float*)d_in[2];
  const float* ln1_b = (const float*)d_in[3];
  const float* w_qkv = (const float*)d_in[4];
  const float* b_qkv = (const float*)d_in[5];
  const float* w_o   = (const float*)d_in[6];
  const float* b_o   = (const float*)d_in[7];
  const float* ln2_g = (const float*)d_in[8];
  const float* ln2_b = (const float*)d_in[9];
  const float* rw    = (const float*)d_in[10];
  const float* rb    = (const float*)d_in[11];
  const float* w1    = (const float*)d_in[12];
  const float* b1    = (const float*)d_in[13];
  const float* w2    = (const float*)d_in[14];
  const float* b2    = (const float*)d_in[15];
  float* out = (float*)d_out;

  char* wsp = (char*)d_ws;
  size_t off = 0;
  auto alloc = [&](size_t bytes)->void*{
    void* p = wsp + off; off += (bytes + 255) & ~(size_t)255; return p;
  };
  u16* wqkv_bf = (u16*)alloc((size_t)3*TD*TD*2);
  u16* wo_bf   = (u16*)alloc((size_t)TD*TD*2);
  u16* w1t     = (u16*)alloc((size_t)TE*TD*TF*2);   // [E][F][D]
  u16* w2t     = (u16*)alloc((size_t)TE*TD*TF*2);   // [E][D][F]
  u16* h2bf    = (u16*)alloc((size_t)TT*TD*2);
  u16* hidden  = (u16*)alloc((size_t)TT*TKK*TF*2);  // [8192][F]
  char* ph1    = (char*)alloc((size_t)44*1024*1024); // phase-1 arena / slot_out
  u16* hbf     = (u16*)ph1;
  u16* qkvbf   = (u16*)(ph1 + (size_t)TT*TD*2);
  u16* ctxbf   = (u16*)(ph1 + (size_t)TT*TD*2 + (size_t)TT*3*TD*2);
  float* slot_out = (float*)ph1;                     // reuses dead phase-1 space
  int*   topidx     = (int*)alloc(TT*2*4);
  float* topw       = (float*)alloc(TT*2*4);
  int*   counts     = (int*)alloc(64);
  int*   offs       = (int*)alloc(64);
  int*   cursors    = (int*)alloc(64);
  int*   assign_tok = (int*)alloc(TT*TKK*4);
  float* assign_w_  = (float*)alloc(TT*TKK*4);
  int*   token_slot = (int*)alloc(TT*TKK*4);
  (void)ws_size; (void)in_sizes; (void)n_in; (void)out_size;

  const dim3 b256(256), b512(512);
  zero_counts_kernel<<<dim3(1), dim3(64), 0, stream>>>(counts);
  cast_bf_kernel<<<dim3(3*TD*TD/4/256), b256, 0, stream>>>(w_qkv, wqkv_bf, 3*TD*TD/4);
  cast_bf_kernel<<<dim3(TD*TD/4/256), b256, 0, stream>>>(w_o, wo_bf, TD*TD/4);
  transpose_cast_kernel<<<dim3(TF/32, TD/32, TE), b256, 0, stream>>>(w1, w1t, TD, TF);
  transpose_cast_kernel<<<dim3(TD/32, TF/32, TE), b256, 0, stream>>>(w2, w2t, TF, TD);
  ln1_kernel<<<dim3(TT), b256, 0, stream>>>(x, ln1_g, ln1_b, hbf);
  gemm256<0><<<dim3(QLD/256, TT/256), b512, 0, stream>>>(
      hbf, wqkv_bf, b_qkv, nullptr, qkvbf, TD, QLD,
      nullptr, nullptr, nullptr, nullptr);
  attn_kernel<<<dim3(TB*TH*16), b256, 0, stream>>>(qkvbf, ctxbf);
  gemm_bt<1><<<dim3(TD/128, TT/128), b256, 0, stream>>>(
      ctxbf, wo_bf, b_o, x, out, nullptr, TD, TD,
      nullptr, nullptr, nullptr, nullptr);
  ln2_router_kernel<<<dim3(TT), b256, 0, stream>>>(
      out, ln2_g, ln2_b, h2bf, rw, rb, counts, topidx, topw);
  offsets_kernel<<<dim3(1), dim3(64), 0, stream>>>(counts, offs, cursors, out + (size_t)TT*TD);
  scatter_kernel<<<dim3(TT/256), b256, 0, stream>>>(
      topidx, topw, cursors, assign_tok, assign_w_, token_slot);
  gemm256<2><<<dim3(TF/256, TE*16), b512, 0, stream>>>(
      h2bf, w1t, b1, nullptr, hidden, TD, TF,
      counts, offs, assign_tok, assign_w_);
  gemm256<3><<<dim3(TD/256, TE*16), b512, 0, stream>>>(
      hidden, w2t, b2, slot_out, nullptr, TF, TD,
      counts, offs, assign_tok, assign_w_);
  combine_kernel<<<dim3(TT*TD/4/256), b256, 0, stream>>>(out, slot_out, token_slot);
}

// Round 4
// 651.380 us; speedup vs baseline: 1.1445x; 1.1445x over previous
//
#include <hip/hip_runtime.h>
#include <hip/hip_bf16.h>

// Problem constants
#define TB 2
#define TS 2048
#define TD 1024
#define TH 16
#define THD 64
#define TE 8
#define TKK 2
#define TF 4096
#define TT (TB*TS)      // 4096 tokens
#define QLD (3*TD)      // 3072

typedef unsigned short u16;
typedef __attribute__((ext_vector_type(8))) __bf16 bf16x8;
typedef __attribute__((ext_vector_type(8))) u16 u16x8;
typedef __attribute__((ext_vector_type(4))) u16 u16x4;
typedef __attribute__((ext_vector_type(4))) float f32x4;

static __device__ __forceinline__ u16 f2bf(float f){
  __hip_bfloat16 h = __float2bfloat16(f);
  return __builtin_bit_cast(u16, h);
}

#define MFMA16(a,b,c) __builtin_amdgcn_mfma_f32_16x16x32_bf16((a),(b),(c),0,0,0)
#define GLL16(g, l) __builtin_amdgcn_global_load_lds( \
    (const __attribute__((address_space(1))) unsigned int*)(g), \
    (__attribute__((address_space(3))) unsigned int*)(l), 16, 0, 0)

// ---------------------------------------------------------------- utilities
__global__ __launch_bounds__(256)
void cast_bf_kernel(const float* __restrict__ in, u16* __restrict__ out, int n4){
  int i = blockIdx.x*256 + threadIdx.x;
  if (i < n4){
    float4 v = ((const float4*)in)[i];
    u16x4 o = { f2bf(v.x), f2bf(v.y), f2bf(v.z), f2bf(v.w) };
    ((u16x4*)out)[i] = o;
  }
}

// out[z][c][r] = (bf16) in[z][r][c]   (R,C multiples of 32)
__global__ __launch_bounds__(256)
void transpose_cast_kernel(const float* __restrict__ in, u16* __restrict__ out, int R, int C){
  __shared__ float tile[32][33];
  const size_t mo = (size_t)blockIdx.z * R * C;
  const float* ip = in + mo;
  u16* op = out + mo;
  const int c0 = blockIdx.x*32, r0 = blockIdx.y*32;
  const int lx = threadIdx.x & 31, ly = threadIdx.x >> 5;   // 32 x 8
#pragma unroll
  for (int i2 = 0; i2 < 4; ++i2)
    tile[ly + i2*8][lx] = ip[(size_t)(r0 + ly + i2*8)*C + c0 + lx];
  __syncthreads();
#pragma unroll
  for (int i2 = 0; i2 < 4; ++i2)
    op[(size_t)(c0 + ly + i2*8)*R + r0 + lx] = f2bf(tile[lx][ly + i2*8]);
}

__global__ void zero_counts_kernel(int* counts){
  if (threadIdx.x < TE) counts[threadIdx.x] = 0;
}

// ---------------------------------------------------------------- layernorm 1
__global__ __launch_bounds__(256)
void ln1_kernel(const float* __restrict__ x, const float* __restrict__ g,
                const float* __restrict__ bb, u16* __restrict__ h){
  const int t = blockIdx.x, tid = threadIdx.x;
  const float4 v = ((const float4*)(x + (size_t)t*TD))[tid];
  float s  = v.x + v.y + v.z + v.w;
  float ss = v.x*v.x + v.y*v.y + v.z*v.z + v.w*v.w;
#pragma unroll
  for (int d = 32; d >= 1; d >>= 1){ s += __shfl_down(s, d); ss += __shfl_down(ss, d); }
  __shared__ float red[8];
  const int lane = tid & 63, wave = tid >> 6;
  if (lane == 0){ red[wave] = s; red[4+wave] = ss; }
  __syncthreads();
  const float S  = red[0]+red[1]+red[2]+red[3];
  const float SS = red[4]+red[5]+red[6]+red[7];
  const float mu = S * (1.f/TD);
  const float rstd = rsqrtf(SS*(1.f/TD) - mu*mu + 1e-5f);
  const float4 gv = ((const float4*)g)[tid];
  const float4 bv = ((const float4*)bb)[tid];
  u16x4 o = { f2bf((v.x-mu)*rstd*gv.x + bv.x),
              f2bf((v.y-mu)*rstd*gv.y + bv.y),
              f2bf((v.z-mu)*rstd*gv.z + bv.z),
              f2bf((v.w-mu)*rstd*gv.w + bv.w) };
  ((u16x4*)(h + (size_t)t*TD))[tid] = o;
}

// ------------------------------------------------- layernorm 2 + fp32 router
__global__ __launch_bounds__(256)
void ln2_router_kernel(const float* __restrict__ xo, const float* __restrict__ g,
                       const float* __restrict__ bb, u16* __restrict__ h2,
                       const float* __restrict__ rw, const float* __restrict__ rb,
                       int* __restrict__ counts, int* __restrict__ topidx,
                       float* __restrict__ topw){
  const int t = blockIdx.x, tid = threadIdx.x;
  const float4 v = ((const float4*)(xo + (size_t)t*TD))[tid];
  float s  = v.x + v.y + v.z + v.w;
  float ss = v.x*v.x + v.y*v.y + v.z*v.z + v.w*v.w;
#pragma unroll
  for (int d = 32; d >= 1; d >>= 1){ s += __shfl_down(s, d); ss += __shfl_down(ss, d); }
  __shared__ float red[8];
  const int lane = tid & 63, wave = tid >> 6;
  if (lane == 0){ red[wave] = s; red[4+wave] = ss; }
  __syncthreads();
  const float S  = red[0]+red[1]+red[2]+red[3];
  const float SS = red[4]+red[5]+red[6]+red[7];
  const float mu = S * (1.f/TD);
  const float rstd = rsqrtf(SS*(1.f/TD) - mu*mu + 1e-5f);
  const float4 gv = ((const float4*)g)[tid];
  const float4 bv = ((const float4*)bb)[tid];
  float hv[4] = { (v.x-mu)*rstd*gv.x + bv.x, (v.y-mu)*rstd*gv.y + bv.y,
                  (v.z-mu)*rstd*gv.z + bv.z, (v.w-mu)*rstd*gv.w + bv.w };
  u16x4 o = { f2bf(hv[0]), f2bf(hv[1]), f2bf(hv[2]), f2bf(hv[3]) };
  ((u16x4*)(h2 + (size_t)t*TD))[tid] = o;

  float acc[TE] = {0,0,0,0,0,0,0,0};
#pragma unroll
  for (int q = 0; q < 4; ++q){
    const int d = tid*4 + q;
    const float4 r0 = ((const float4*)(rw + (size_t)d*TE))[0];
    const float4 r1 = ((const float4*)(rw + (size_t)d*TE))[1];
    acc[0] += hv[q]*r0.x; acc[1] += hv[q]*r0.y; acc[2] += hv[q]*r0.z; acc[3] += hv[q]*r0.w;
    acc[4] += hv[q]*r1.x; acc[5] += hv[q]*r1.y; acc[6] += hv[q]*r1.z; acc[7] += hv[q]*r1.w;
  }
#pragma unroll
  for (int d = 32; d >= 1; d >>= 1)
#pragma unroll
    for (int e = 0; e < TE; ++e) acc[e] += __shfl_down(acc[e], d);
  __shared__ float racc[4][TE];
  if (lane == 0)
#pragma unroll
    for (int e = 0; e < TE; ++e) racc[wave][e] = acc[e];
  __syncthreads();
  if (tid == 0){
    float lg[TE];
#pragma unroll
    for (int e = 0; e < TE; ++e)
      lg[e] = racc[0][e] + racc[1][e] + racc[2][e] + racc[3][e] + rb[e];
    int e1 = 0;
    for (int e = 1; e < TE; ++e) if (lg[e] > lg[e1]) e1 = e;
    int e2 = -1;
    for (int e = 0; e < TE; ++e){ if (e == e1) continue; if (e2 < 0 || lg[e] > lg[e2]) e2 = e; }
    const float w1 = 1.f / (1.f + __expf(lg[e2] - lg[e1]));
    const float w2 = 1.f / (1.f + __expf(lg[e1] - lg[e2]));
    topidx[t*2]   = e1;  topidx[t*2+1] = e2;
    topw[t*2]     = w1;  topw[t*2+1]   = w2;
    atomicAdd(&counts[e1], 1);
    atomicAdd(&counts[e2], 1);
  }
}

__global__ void offsets_kernel(const int* __restrict__ counts, int* __restrict__ offs,
                               int* __restrict__ cursors, float* __restrict__ load_out){
  if (threadIdx.x == 0){
    int off = 0;
    for (int e = 0; e < TE; ++e){
      offs[e] = off; cursors[e] = off; off += counts[e];
      load_out[e] = (float)counts[e];
    }
  }
}

__global__ __launch_bounds__(256)
void scatter_kernel(const int* __restrict__ topidx, const float* __restrict__ topw,
                    int* __restrict__ cursors, int* __restrict__ assign_tok,
                    float* __restrict__ assign_w, int* __restrict__ token_slot){
  const int t = blockIdx.x*256 + threadIdx.x;
  if (t >= TT) return;
#pragma unroll
  for (int k = 0; k < 2; ++k){
    const int e = topidx[t*2 + k];
    const int pos = atomicAdd(&cursors[e], 1);
    assign_tok[pos] = t;
    assign_w[pos]   = topw[t*2 + k];
    token_slot[t*2 + k] = pos;
  }
}

// ------------------------------------------ 256x256 8-phase GEMM, round-4 fix:
// * conflict-free XOR swizzle: byte ^= ((row&7)<<4)  (read side) with the SAME
//   involution pre-applied to the global source column (linear gload_lds dest).
// * zigzag quadrant order (0,0)->(0,1)->(1,1)->(1,0): A regs held over first
//   pair, B0 regs held across the tile -> ds_reads/phase = {12,4,8,0}
//   = 24KB/tile/wave (minimal operand traffic).
// * counted vmcnt(4) at tile boundaries only; stages placed strictly after
//   each LDS region's last reader.
#define LD8(base, off) (*(const bf16x8*)((const char*)(base) + (off)))
#define STG2(rp, ktv, dst) do{ \
    GLL16((rp)[0] + (size_t)(ktv)*64, (dst) + tid*8); \
    GLL16((rp)[1] + (size_t)(ktv)*64, (dst) + 4096 + tid*8); }while(0)

#define BARRIER_IN do{ __builtin_amdgcn_s_barrier(); \
    asm volatile("s_waitcnt lgkmcnt(0)" ::: "memory"); \
    __builtin_amdgcn_sched_barrier(0); }while(0)

#define READ_A(BUF) do{ \
    ax0=LD8(BUF,offA[0][0]); ax1=LD8(BUF,offA[1][0]); ax2=LD8(BUF,offA[2][0]); ax3=LD8(BUF,offA[3][0]); \
    ay0=LD8(BUF,offA[0][1]); ay1=LD8(BUF,offA[1][1]); ay2=LD8(BUF,offA[2][1]); ay3=LD8(BUF,offA[3][1]); }while(0)
#define READ_B(BUF,X0,X1,Y0,Y1) do{ \
    X0=LD8(BUF,offB[0][0]); X1=LD8(BUF,offB[1][0]); \
    Y0=LD8(BUF,offB[0][1]); Y1=LD8(BUF,offB[1][1]); }while(0)

#define CLUSTER(H,G,BX0,BX1,BY0,BY1) do{ \
    __builtin_amdgcn_s_setprio(1); \
    acc[H][G][0][0]=MFMA16(ax0,BX0,acc[H][G][0][0]); acc[H][G][0][0]=MFMA16(ay0,BY0,acc[H][G][0][0]); \
    acc[H][G][1][0]=MFMA16(ax1,BX0,acc[H][G][1][0]); acc[H][G][1][0]=MFMA16(ay1,BY0,acc[H][G][1][0]); \
    acc[H][G][2][0]=MFMA16(ax2,BX0,acc[H][G][2][0]); acc[H][G][2][0]=MFMA16(ay2,BY0,acc[H][G][2][0]); \
    acc[H][G][3][0]=MFMA16(ax3,BX0,acc[H][G][3][0]); acc[H][G][3][0]=MFMA16(ay3,BY0,acc[H][G][3][0]); \
    acc[H][G][0][1]=MFMA16(ax0,BX1,acc[H][G][0][1]); acc[H][G][0][1]=MFMA16(ay0,BY1,acc[H][G][0][1]); \
    acc[H][G][1][1]=MFMA16(ax1,BX1,acc[H][G][1][1]); acc[H][G][1][1]=MFMA16(ay1,BY1,acc[H][G][1][1]); \
    acc[H][G][2][1]=MFMA16(ax2,BX1,acc[H][G][2][1]); acc[H][G][2][1]=MFMA16(ay2,BY1,acc[H][G][2][1]); \
    acc[H][G][3][1]=MFMA16(ax3,BX1,acc[H][G][3][1]); acc[H][G][3][1]=MFMA16(ay3,BY1,acc[H][G][3][1]); \
    __builtin_amdgcn_s_setprio(0); }while(0)

template<int MODE>
__global__ __launch_bounds__(512, 2)
void gemm256(const u16* __restrict__ A, const u16* __restrict__ Bt,
             const float* __restrict__ bias,
             float* __restrict__ outF, u16* __restrict__ outB,
             const int K, const int N,
             const int* __restrict__ counts, const int* __restrict__ offs,
             const int* __restrict__ assign_tok, const float* __restrict__ assign_w)
{
  __shared__ u16 lds[8][8192];   // 0,1=A-even halves; 2,3=B-even; 4,5=A-odd; 6,7=B-odd
  const int tid = threadIdx.x;
  const int n0 = blockIdx.x*256;
  int row0 = 0, slotbase = 0, cntRem = 256, slotEnd = 0;
  if (MODE == 0){
    row0 = blockIdx.y*256;
  } else {
    const int e = blockIdx.y >> 4, mt = blockIdx.y & 15;
    const int cnt = counts[e];
    if (mt*256 >= cnt) return;
    slotbase = offs[e] + mt*256;
    slotEnd  = offs[e] + cnt;
    cntRem   = cnt - mt*256; if (cntRem > 256) cntRem = 256;
    Bt   += (size_t)e*K*N;
    bias += (size_t)e*N;
  }
  // staging: thread t -> LDS row (t>>3), 16B slot (t&7) [linear dest];
  // source column pre-swizzled by the same involution the reader uses.
  const int srow = tid >> 3;
  const int csrc = (((tid & 7) ^ (srow & 7)) * 8);
  const u16* aRow[4]; const u16* bRow[4];
#pragma unroll
  for (int p = 0; p < 4; ++p){
    const int r = p*64 + srow;
    if (MODE == 0){
      aRow[p] = A + (size_t)(row0 + r)*K + csrc;
    } else if (MODE == 2){
      int s2 = slotbase + r; if (s2 > slotEnd-1) s2 = slotEnd-1;
      aRow[p] = A + (size_t)assign_tok[s2]*K + csrc;
    } else {
      int s2 = slotbase + r; if (s2 > slotEnd-1) s2 = slotEnd-1;
      aRow[p] = A + (size_t)s2*K + csrc;
    }
    bRow[p] = Bt + (size_t)(n0 + r)*K + csrc;
  }

  const int lane = tid & 63, wave = tid >> 6;
  const int wr = wave >> 2, wc = wave & 3;
  const int r16 = lane & 15, kgr = lane >> 4;
  int offA[4][2], offB[2][2];
#pragma unroll
  for (int f = 0; f < 4; ++f)
#pragma unroll
    for (int kk = 0; kk < 2; ++kk){
      const int row = wr*64 + f*16 + r16;
      offA[f][kk] = row*128 + (((kk*4 + kgr) ^ (row & 7)) << 4);
    }
#pragma unroll
  for (int g = 0; g < 2; ++g)
#pragma unroll
    for (int kk = 0; kk < 2; ++kk){
      const int row = wc*32 + g*16 + r16;
      offB[g][kk] = row*128 + (((kk*4 + kgr) ^ (row & 7)) << 4);
    }
  const f32x4 z4 = {0.f,0.f,0.f,0.f};
  f32x4 acc[2][2][4][2];
#pragma unroll
  for (int a0 = 0; a0 < 2; ++a0)
#pragma unroll
    for (int a1 = 0; a1 < 2; ++a1)
#pragma unroll
      for (int a2 = 0; a2 < 4; ++a2)
#pragma unroll
        for (int a3 = 0; a3 < 2; ++a3) acc[a0][a1][a2][a3] = z4;

  bf16x8 ax0,ax1,ax2,ax3, ay0,ay1,ay2,ay3;
  bf16x8 b0x0,b0x1,b0y0,b0y1, b1x0,b1x1,b1y0,b1y1;

  // prologue: T0 fully + T1.A0 + T1.B0   (order matters for vmcnt counting)
  STG2(aRow+0, 0, lds[0]); STG2(aRow+2, 0, lds[1]);
  STG2(bRow+0, 0, lds[2]); STG2(bRow+2, 0, lds[3]);
  STG2(aRow+0, 1, lds[4]); STG2(bRow+0, 1, lds[6]);
  asm volatile("s_waitcnt vmcnt(4)" ::: "memory");
  __builtin_amdgcn_s_barrier();

  const int nk = K >> 6, niter = nk >> 1;
  for (int it2 = 0; it2 < niter; ++it2){
    const int kt = it2*2;
    const bool last = (it2 == niter-1);
    // ---- tile even (kt): A in lds[0,1], B in lds[2,3]
    READ_A(lds[0]); READ_B(lds[2], b0x0,b0x1,b0y0,b0y1);
    STG2(aRow+2, kt+1, lds[5]);                       // T(kt+1).A1
    BARRIER_IN; CLUSTER(0,0, b0x0,b0x1,b0y0,b0y1);
    __builtin_amdgcn_s_barrier();

    READ_B(lds[3], b1x0,b1x1,b1y0,b1y1);
    STG2(bRow+2, kt+1, lds[7]);                       // T(kt+1).B1
    BARRIER_IN; CLUSTER(0,1, b1x0,b1x1,b1y0,b1y1);
    __builtin_amdgcn_s_barrier();

    READ_A(lds[1]);
    if (!last) STG2(aRow+0, kt+2, lds[0]);            // T(kt+2).A0
    BARRIER_IN; CLUSTER(1,1, b1x0,b1x1,b1y0,b1y1);
    __builtin_amdgcn_s_barrier();

    if (!last) STG2(bRow+0, kt+2, lds[2]);            // T(kt+2).B0
    BARRIER_IN; CLUSTER(1,0, b0x0,b0x1,b0y0,b0y1);
    if (last) asm volatile("s_waitcnt vmcnt(0)" ::: "memory");
    else      asm volatile("s_waitcnt vmcnt(4)" ::: "memory");
    __builtin_amdgcn_s_barrier();

    // ---- tile odd (kt+1): A in lds[4,5], B in lds[6,7]
    READ_A(lds[4]); READ_B(lds[6], b0x0,b0x1,b0y0,b0y1);
    if (!last) STG2(aRow+2, kt+2, lds[1]);            // T(kt+2).A1
    BARRIER_IN; CLUSTER(0,0, b0x0,b0x1,b0y0,b0y1);
    __builtin_amdgcn_s_barrier();

    READ_B(lds[7], b1x0,b1x1,b1y0,b1y1);
    if (!last) STG2(bRow+2, kt+2, lds[3]);            // T(kt+2).B1
    BARRIER_IN; CLUSTER(0,1, b1x0,b1x1,b1y0,b1y1);
    __builtin_amdgcn_s_barrier();

    READ_A(lds[5]);
    if (!last) STG2(aRow+0, kt+3, lds[4]);            // T(kt+3).A0
    BARRIER_IN; CLUSTER(1,1, b1x0,b1x1,b1y0,b1y1);
    __builtin_amdgcn_s_barrier();

    if (!last) STG2(bRow+0, kt+3, lds[6]);            // T(kt+3).B0
    BARRIER_IN; CLUSTER(1,0, b0x0,b0x1,b0y0,b0y1);
    if (!last) asm volatile("s_waitcnt vmcnt(4)" ::: "memory");
    __builtin_amdgcn_s_barrier();
  }

  // epilogue
#pragma unroll
  for (int qr = 0; qr < 2; ++qr)
#pragma unroll
  for (int f = 0; f < 4; ++f)
#pragma unroll
  for (int rr = 0; rr < 4; ++rr){
    const int rl = qr*128 + wr*64 + f*16 + kgr*4 + rr;
#pragma unroll
    for (int qc = 0; qc < 2; ++qc)
#pragma unroll
    for (int g = 0; g < 2; ++g){
      const int col = n0 + qc*128 + wc*32 + g*16 + r16;
      float v = acc[qr][qc][f][g][rr];
      if (MODE == 0){
        outB[(size_t)(row0 + rl)*QLD + col] = f2bf(v + bias[col]);
      } else if (MODE == 2){
        if (rl < cntRem){
          v += bias[col];
          const float t = tanhf(0.7978845608028654f*(v + 0.044715f*v*v*v));
          outB[(size_t)(slotbase + rl)*TF + col] = f2bf(0.5f*v*(1.f + t));
        }
      } else {
        if (rl < cntRem)
          outF[(size_t)(slotbase + rl)*TD + col] = (v + bias[col])*assign_w[slotbase + rl];
      }
    }
  }
}

// ---------------------------------------------------------------- GEMM 128^2
// (kept for O-proj: N=1024 would under-fill the chip at 256^2 tiles)
template<int MODE>
__global__ __launch_bounds__(256)
void gemm_bt(const u16* __restrict__ A, const u16* __restrict__ Bt,
             const float* __restrict__ bias, const float* __restrict__ resid,
             float* __restrict__ outF, u16* __restrict__ outB,
             int K, int N,
             const int* __restrict__ counts, const int* __restrict__ offs,
             const int* __restrict__ assign_tok, const float* __restrict__ assign_w)
{
  __shared__ u16 As[2][128*32];
  __shared__ u16 Bs[2][128*32];
  const int tid = threadIdx.x;
  const int n0  = blockIdx.x * 128;
  int row0 = blockIdx.y * 128;
  const int srow = tid >> 2, skseg = tid & 3;
  const u16* aptr[2];
  const u16* bptr[2];
#pragma unroll
  for (int it = 0; it < 2; ++it){
    const int r = it*64 + srow;
    aptr[it] = A + (size_t)(row0 + r)*K + skseg*8;
    bptr[it] = Bt + (size_t)(n0 + it*64 + srow)*K + skseg*8;
  }

#define STAGE(buf, kt) do {                                        \
    _Pragma("unroll")                                              \
    for (int it = 0; it < 2; ++it){                                \
      GLL16(aptr[it] + (size_t)(kt)*32, &As[buf][it*2048 + tid*8]);\
      GLL16(bptr[it] + (size_t)(kt)*32, &Bs[buf][it*2048 + tid*8]);\
    } } while(0)

  const int lane = tid & 63, wave = tid >> 6;
  const int wm = (wave >> 1) * 64, wn = (wave & 1) * 64;
  const int r16 = lane & 15, kgr = lane >> 4;
  const f32x4 z4 = {0.f,0.f,0.f,0.f};
  f32x4 acc[4][4];
#pragma unroll
  for (int i = 0; i < 4; ++i)
#pragma unroll
    for (int j = 0; j < 4; ++j) acc[i][j] = z4;

  STAGE(0, 0);
  __syncthreads();
  const int nk = K >> 5;
  for (int kt = 0; kt < nk; ++kt){
    const int cur = kt & 1;
    if (kt + 1 < nk) STAGE(cur ^ 1, kt + 1);
    bf16x8 a[4], b[4];
#pragma unroll
    for (int i = 0; i < 4; ++i)
      a[i] = *(const bf16x8*)&As[cur][(wm + i*16 + r16)*32 + kgr*8];
#pragma unroll
    for (int j = 0; j < 4; ++j)
      b[j] = *(const bf16x8*)&Bs[cur][(wn + j*16 + r16)*32 + kgr*8];
#pragma unroll
    for (int i = 0; i < 4; ++i)
#pragma unroll
      for (int j = 0; j < 4; ++j)
        acc[i][j] = MFMA16(a[i], b[j], acc[i][j]);
    __syncthreads();
  }
#undef STAGE

#pragma unroll
  for (int i = 0; i < 4; ++i){
#pragma unroll
    for (int r = 0; r < 4; ++r){
      const int row = wm + i*16 + kgr*4 + r;
#pragma unroll
      for (int j = 0; j < 4; ++j){
        const int col = n0 + wn + j*16 + r16;
        float v = acc[i][j][r];
        const size_t idx = (size_t)(row0 + row)*TD + col;
        outF[idx] = v + bias[col] + resid[idx];
      }
    }
  }
  (void)counts; (void)offs; (void)assign_tok; (void)assign_w; (void)outB; (void)N;
}

// ------------------------------------------------------- flash attention
__global__ __launch_bounds__(256)
void attn_kernel(const u16* __restrict__ qkv, u16* __restrict__ ctx){
  const int blk = blockIdx.x;
  const int pq = blk & 15, bh = blk >> 4;
  const int b = bh >> 4, h = bh & 15;
  const int tid = threadIdx.x, lane = tid & 63, wave = tid >> 6;
  const int r16 = lane & 15, kgr = lane >> 4;
  const size_t base = (size_t)b * TS * QLD;
  const u16* Q  = qkv + base + h*THD;
  const u16* Kp = qkv + base + TD + h*THD;
  const u16* Vp = qkv + base + 2*TD + h*THD;

  __shared__ u16 VT[2][64*64];     // V^T [hd][kv], XOR-swizzled
  __shared__ u16 Plds[4][16*64];   // per-wave P [q][kv], XOR-swizzled

  const int kvr0 = tid >> 3,          hs0 = tid & 7;
  const int kvr1 = (tid + 256) >> 3,  hs1 = tid & 7;
  const f32x4 z4 = {0.f,0.f,0.f,0.f};

  for (int qsel = 0; qsel < 2; ++qsel){
    const int qt = qsel ? (31 - pq) : pq;
    const int qw = qt*64 + wave*16;

    const bf16x8 qa0 = *(const bf16x8*)&Q[(size_t)(qw + r16)*QLD + kgr*8];
    const bf16x8 qa1 = *(const bf16x8*)&Q[(size_t)(qw + r16)*QLD + 32 + kgr*8];

    f32x4 O[4] = { z4, z4, z4, z4 };
    float m_r = -1e30f;
    float l_r = 0.f;

    u16x8 v0 = *(const u16x8*)&Vp[(size_t)kvr0*QLD + hs0*8];
    u16x8 v1 = *(const u16x8*)&Vp[(size_t)kvr1*QLD + hs1*8];

    __syncthreads();

    for (int kt = 0; kt <= qt; ++kt){
      const int kv0 = kt*64;
      u16* vt = &VT[kt & 1][0];
#pragma unroll
      for (int jj = 0; jj < 8; ++jj)
        vt[((hs0*8 + jj)*64 + kvr0) ^ (hs0<<3)] = v0[jj];
#pragma unroll
      for (int jj = 0; jj < 8; ++jj)
        vt[((hs1*8 + jj)*64 + kvr1) ^ (hs1<<3)] = v1[jj];
      if (kt < qt){
        v0 = *(const u16x8*)&Vp[(size_t)(kv0 + 64 + kvr0)*QLD + hs0*8];
        v1 = *(const u16x8*)&Vp[(size_t)(kv0 + 64 + kvr1)*QLD + hs1*8];
      }
      f32x4 s[4];
      __builtin_amdgcn_s_setprio(1);
#pragma unroll
      for (int j = 0; j < 4; ++j){
        const bf16x8 k0 = *(const bf16x8*)&Kp[(size_t)(kv0 + j*16 + r16)*QLD + kgr*8];
        const bf16x8 k1 = *(const bf16x8*)&Kp[(size_t)(kv0 + j*16 + r16)*QLD + 32 + kgr*8];
        s[j] = MFMA16(k0, qa0, z4);
        s[j] = MFMA16(k1, qa1, s[j]);
      }
      __builtin_amdgcn_s_setprio(0);
      const bool diag = (kt == qt);
      float mx = -3e38f;
#pragma unroll
      for (int j = 0; j < 4; ++j)
#pragma unroll
        for (int r = 0; r < 4; ++r){
          float v = s[j][r] * 0.125f;
          if (diag && (kv0 + j*16 + kgr*4 + r > qw + r16)) v += -1e9f;
          s[j][r] = v;
          mx = fmaxf(mx, v);
        }
      mx = fmaxf(mx, __shfl_xor(mx, 16));
      mx = fmaxf(mx, __shfl_xor(mx, 32));
      const float mn = fmaxf(m_r, mx);
      const float al = __expf(m_r - mn);
      m_r = mn;
      float rs = 0.f;
#pragma unroll
      for (int j = 0; j < 4; ++j){
        u16x4 pw;
#pragma unroll
        for (int r = 0; r < 4; ++r){
          const float p = __expf(s[j][r] - mn);
          rs += p;
          pw[r] = f2bf(p);
        }
        *(u16x4*)&Plds[wave][(r16*64 + j*16 + kgr*4) ^ ((r16&7)<<3)] = pw;
      }
      rs += __shfl_xor(rs, 16);
      rs += __shfl_xor(rs, 32);
      l_r = l_r*al + rs;
      float alr[4];
#pragma unroll
      for (int r = 0; r < 4; ++r)
        alr[r] = __shfl(al, (lane & 48) | (kgr*4 + r));
#pragma unroll
      for (int c = 0; c < 4; ++c)
#pragma unroll
        for (int r = 0; r < 4; ++r) O[c][r] *= alr[r];
      __syncthreads();
      __builtin_amdgcn_s_setprio(1);
#pragma unroll
      for (int kbl = 0; kbl < 2; ++kbl){
        const bf16x8 pa = *(const bf16x8*)&Plds[wave][(r16*64 + kbl*32 + kgr*8) ^ ((r16&7)<<3)];
#pragma unroll
        for (int c = 0; c < 4; ++c){
          const int hd = c*16 + r16;
          const bf16x8 vb = *(const bf16x8*)&vt[(hd*64 + kbl*32 + kgr*8) ^ (((hd>>3)&7)<<3)];
          O[c] = MFMA16(pa, vb, O[c]);
        }
      }
      __builtin_amdgcn_s_setprio(0);
    }
    u16* cp = ctx + (size_t)b*TS*TD + h*THD;
#pragma unroll
    for (int r = 0; r < 4; ++r){
      const float lr = __shfl(l_r, (lane & 48) | (kgr*4 + r));
      const float inv = 1.f / lr;
      const int qrow = qw + kgr*4 + r;
#pragma unroll
      for (int c = 0; c < 4; ++c)
        cp[(size_t)qrow*TD + c*16 + r16] = f2bf(O[c][r] * inv);
    }
  }
}

// ---------------------------------------------------------------- combine
__global__ __launch_bounds__(256)
void combine_kernel(float* __restrict__ out, const float* __restrict__ slot_out,
                    const int* __restrict__ token_slot){
  const int i = blockIdx.x*256 + threadIdx.x;   // over TT*TD/4
  const int t = i >> 8, c = i & 255;
  const int s0 = token_slot[t*2], s1 = token_slot[t*2+1];
  const float4 a = ((const float4*)out)[i];
  const float4 u = ((const float4*)slot_out)[(size_t)s0*256 + c];
  const float4 w = ((const float4*)slot_out)[(size_t)s1*256 + c];
  float4 o = { a.x+u.x+w.x, a.y+u.y+w.y, a.z+u.z+w.z, a.w+u.w+w.w };
  ((float4*)out)[i] = o;
}

// ---------------------------------------------------------------- launcher
extern "C" void kernel_launch(void* const* d_in, const int* in_sizes, int n_in,
                              void* d_out, int out_size, void* d_ws, size_t ws_size,
                              hipStream_t stream){
  const float* x     = (const float*)d_in[0];
  const float* ln1_g = (const float*)d_in[2];
  const float* ln1_b = (const float*)d_in[3];
  const float* w_qkv = (const float*)d_in[4];
  const float* b_qkv = (const float*)d_in[5];
  const float* w_o   = (const float*)d_in[6];
  const float* b_o   = (const float*)d_in[7];
  const float* ln2_g = (const float*)d_in[8];
  const float* ln2_b = (const float*)d_in[9];
  const float* rw    = (const float*)d_in[10];
  const float* rb    = (const float*)d_in[11];
  const float* w1    = (const float*)d_in[12];
  const float* b1    = (const float*)d_in[13];
  const float* w2    = (const float*)d_in[14];
  const float* b2    = (const float*)d_in[15];
  float* out = (float*)d_out;

  char* wsp = (char*)d_ws;
  size_t off = 0;
  auto alloc = [&](size_t bytes)->void*{
    void* p = wsp + off; off += (bytes + 255) & ~(size_t)255; return p;
  };
  u16* wqkv_bf = (u16*)alloc((size_t)3*TD*TD*2);
  u16* wo_bf   = (u16*)alloc((size_t)TD*TD*2);
  u16* w1t     = (u16*)alloc((size_t)TE*TD*TF*2);   // [E][F][D]
  u16* w2t     = (u16*)alloc((size_t)TE*TD*TF*2);   // [E][D][F]
  u16* h2bf    = (u16*)alloc((size_t)TT*TD*2);
  u16* hidden  = (u16*)alloc((size_t)TT*TKK*TF*2);  // [8192][F]
  char* ph1    = (char*)alloc((size_t)44*1024*1024); // phase-1 arena / slot_out
  u16* hbf     = (u16*)ph1;
  u16* qkvbf   = (u16*)(ph1 + (size_t)TT*TD*2);
  u16* ctxbf   = (u16*)(ph1 + (size_t)TT*TD*2 + (size_t)TT*3*TD*2);
  float* slot_out = (float*)ph1;                     // reuses dead phase-1 space
  int*   topidx     = (int*)alloc(TT*2*4);
  float* topw       = (float*)alloc(TT*2*4);
  int*   counts     = (int*)alloc(64);
  int*   offs       = (int*)alloc(64);
  int*   cursors    = (int*)alloc(64);
  int*   assign_tok = (int*)alloc(TT*TKK*4);
  float* assign_w_  = (float*)alloc(TT*TKK*4);
  int*   token_slot = (int*)alloc(TT*TKK*4);
  (void)ws_size; (void)in_sizes; (void)n_in; (void)out_size;

  const dim3 b256(256), b512(512);
  zero_counts_kernel<<<dim3(1), dim3(64), 0, stream>>>(counts);
  cast_bf_kernel<<<dim3(3*TD*TD/4/256), b256, 0, stream>>>(w_qkv, wqkv_bf, 3*TD*TD/4);
  cast_bf_kernel<<<dim3(TD*TD/4/256), b256, 0, stream>>>(w_o, wo_bf, TD*TD/4);
  transpose_cast_kernel<<<dim3(TF/32, TD/32, TE), b256, 0, stream>>>(w1, w1t, TD, TF);
  transpose_cast_kernel<<<dim3(TD/32, TF/32, TE), b256, 0, stream>>>(w2, w2t, TF, TD);
  ln1_kernel<<<dim3(TT), b256, 0, stream>>>(x, ln1_g, ln1_b, hbf);
  gemm256<0><<<dim3(QLD/256, TT/256), b512, 0, stream>>>(
      hbf, wqkv_bf, b_qkv, nullptr, qkvbf, TD, QLD,
      nullptr, nullptr, nullptr, nullptr);
  attn_kernel<<<dim3(TB*TH*16), b256, 0, stream>>>(qkvbf, ctxbf);
  gemm_bt<1><<<dim3(TD/128, TT/128), b256, 0, stream>>>(
      ctxbf, wo_bf, b_o, x, out, nullptr, TD, TD,
      nullptr, nullptr, nullptr, nullptr);
  ln2_router_kernel<<<dim3(TT), b256, 0, stream>>>(
      out, ln2_g, ln2_b, h2bf, rw, rb, counts, topidx, topw);
  offsets_kernel<<<dim3(1), dim3(64), 0, stream>>>(counts, offs, cursors, out + (size_t)TT*TD);
  scatter_kernel<<<dim3(TT/256), b256, 0, stream>>>(
      topidx, topw, cursors, assign_tok, assign_w_, token_slot);
  gemm256<2><<<dim3(TF/256, TE*16), b512, 0, stream>>>(
      h2bf, w1t, b1, nullptr, hidden, TD, TF,
      counts, offs, assign_tok, assign_w_);
  gemm256<3><<<dim3(TD/256, TE*16), b512, 0, stream>>>(
      hidden, w2t, b2, slot_out, nullptr, TF, TD,
      counts, offs, assign_tok, assign_w_);
  combine_kernel<<<dim3(TT*TD/4/256), b256, 0, stream>>>(out, slot_out, token_slot);
}